// Round 2
// baseline (478.345 us; speedup 1.0000x reference)
//
#include <hip/hip_runtime.h>
#include <hip/hip_bf16.h>
#include <stdint.h>

#define DIMSZ 1024
#define NHEADS 16
#define HD 64
#define BB 2
#define L_IN 1536
#define L_CTX 256
#define NTOT 1792   // L_CTX + L_IN

typedef __attribute__((ext_vector_type(8))) short bf16x8;
typedef __attribute__((ext_vector_type(4))) float f32x4;
typedef __attribute__((ext_vector_type(16))) float f32x16;

__device__ inline unsigned short f2bf(float f) {
    union { float f; unsigned u; } v; v.f = f;
    unsigned r = v.u + 0x7fffu + ((v.u >> 16) & 1u);
    return (unsigned short)(r >> 16);
}

__device__ inline f32x4 zero4() {
    f32x4 v;
    #pragma unroll
    for (int i = 0; i < 4; i++) v[i] = 0.f;
    return v;
}
__device__ inline f32x16 zero16() {
    f32x16 v;
    #pragma unroll
    for (int i = 0; i < 16; i++) v[i] = 0.f;
    return v;
}

// ---------------------------------------------------------------------------
// Generic GEMM:  out[omap(r)][n] = sum_k A[amap(r)][k] * W[k][n] + bias[n]
// A: fp32 or bf16, row-major, lda = 1024 (= K). W: fp32 row-major (1024 x Nld).
// out: fp32, ld = Nld. map(r) = r + base + (r / chunk) * extra.
// 128x128 tile, BK=64, 256 threads (4 waves, each 64x64), 16x16x32 bf16 MFMA.
// LDS XOR-swizzle: byte ^= (row&7)<<4 within each row's 128B — frag reads are
// 16B/lane over 16 rows -> spread across banks (<=2-way, free per m136).
// ---------------------------------------------------------------------------
template<bool A_BF16>
__global__ __launch_bounds__(256) void gemm_kernel(
    const void* __restrict__ Aptr, const float* __restrict__ W,
    const float* __restrict__ bias, float* __restrict__ out, int Nld,
    int a_chunk, int a_base, int a_extra,
    int o_chunk, int o_base, int o_extra)
{
    __shared__ unsigned short Asm[128 * 64];
    __shared__ unsigned short Bsm[128 * 64];
    const int r0 = blockIdx.x * 128, n0 = blockIdx.y * 128;
    const int t = threadIdx.x;
    const int lane = t & 63, wid = t >> 6;
    const int wr = wid >> 1, wc = wid & 1;
    const int g4 = lane >> 4, l16 = lane & 15;

    f32x4 acc[4][4];
    #pragma unroll
    for (int mi = 0; mi < 4; mi++)
        #pragma unroll
        for (int ni = 0; ni < 4; ni++) acc[mi][ni] = zero4();

    for (int k0 = 0; k0 < 1024; k0 += 64) {
        __syncthreads();
        // ---- stage A tile: 128 rows x 64 k ----
        #pragma unroll
        for (int i = 0; i < 8; i++) {
            int idx = i * 256 + t;
            int row = idx >> 4, c4 = idx & 15;
            int gr = r0 + row;
            int amem = gr + a_base + (gr / a_chunk) * a_extra;
            unsigned short e0, e1, e2, e3;
            if constexpr (A_BF16) {
                const unsigned short* A16 = (const unsigned short*)Aptr;
                ushort4 v = *(const ushort4*)(A16 + (size_t)amem * 1024 + k0 + c4 * 4);
                e0 = v.x; e1 = v.y; e2 = v.z; e3 = v.w;
            } else {
                float4 v = *(const float4*)((const float*)Aptr + (size_t)amem * 1024 + k0 + c4 * 4);
                e0 = f2bf(v.x); e1 = f2bf(v.y); e2 = f2bf(v.z); e3 = f2bf(v.w);
            }
            int byte = row * 128 + (((c4 * 8) ^ ((row & 7) << 4)));
            uint2 val; val.x = (unsigned)e0 | ((unsigned)e1 << 16);
            val.y = (unsigned)e2 | ((unsigned)e3 << 16);
            *(uint2*)((char*)Asm + byte) = val;
        }
        // ---- stage B^T tile: 128 n x 64 k ----
        #pragma unroll
        for (int i = 0; i < 8; i++) {
            int idx = i * 256 + t;
            int n = idx & 127, kq = idx >> 7;
            const float* Wp = W + (size_t)(k0 + kq * 4) * Nld + n0 + n;
            unsigned short e0 = f2bf(Wp[0]);
            unsigned short e1 = f2bf(Wp[Nld]);
            unsigned short e2 = f2bf(Wp[2 * (size_t)Nld]);
            unsigned short e3 = f2bf(Wp[3 * (size_t)Nld]);
            int byte = n * 128 + (((kq * 8) ^ ((n & 7) << 4)));
            uint2 val; val.x = (unsigned)e0 | ((unsigned)e1 << 16);
            val.y = (unsigned)e2 | ((unsigned)e3 << 16);
            *(uint2*)((char*)Bsm + byte) = val;
        }
        __syncthreads();
        // ---- compute ----
        #pragma unroll
        for (int kk = 0; kk < 2; kk++) {
            bf16x8 a[4], b[4];
            #pragma unroll
            for (int mi = 0; mi < 4; mi++) {
                int row = wr * 64 + mi * 16 + l16;
                int byte = row * 128 + ((kk * 64 + g4 * 16) ^ ((row & 7) << 4));
                a[mi] = *(const bf16x8*)((const char*)Asm + byte);
            }
            #pragma unroll
            for (int ni = 0; ni < 4; ni++) {
                int col = wc * 64 + ni * 16 + l16;
                int byte = col * 128 + ((kk * 64 + g4 * 16) ^ ((col & 7) << 4));
                b[ni] = *(const bf16x8*)((const char*)Bsm + byte);
            }
            #pragma unroll
            for (int mi = 0; mi < 4; mi++)
                #pragma unroll
                for (int ni = 0; ni < 4; ni++)
                    acc[mi][ni] = __builtin_amdgcn_mfma_f32_16x16x32_bf16(
                        a[mi], b[ni], acc[mi][ni], 0, 0, 0);
        }
    }
    // ---- epilogue: C/D layout col=lane&15, row=(lane>>4)*4+reg ----
    #pragma unroll
    for (int mi = 0; mi < 4; mi++)
        #pragma unroll
        for (int ni = 0; ni < 4; ni++) {
            int col = n0 + wc * 64 + ni * 16 + l16;
            float bv = bias[col];
            #pragma unroll
            for (int r = 0; r < 4; r++) {
                int row = r0 + wr * 64 + mi * 16 + g4 * 4 + r;
                int orow = row + o_base + (row / o_chunk) * o_extra;
                out[(size_t)orow * Nld + col] = acc[mi][ni][r] + bv;
            }
        }
}

// ---------------------------------------------------------------------------
// Fused RMSNorm + weight + RoPE + scale + layout. One block per (b,n) row.
// qkv: fp32 (B,NTOT,3072). Writes Q,K bf16 (B,H,NTOT,64), V^T bf16 (B,H,64,NTOT).
// ---------------------------------------------------------------------------
__global__ __launch_bounds__(256) void norm_rope_kernel(
    const float* __restrict__ qkv,
    const float* __restrict__ qw_in, const float* __restrict__ kw_in,
    const float* __restrict__ qw_ctx, const float* __restrict__ kw_ctx,
    const float* __restrict__ cosT, const float* __restrict__ sinT,
    unsigned short* __restrict__ Q, unsigned short* __restrict__ K,
    unsigned short* __restrict__ Vt)
{
    int bn = blockIdx.x;
    int b = bn / NTOT, n = bn % NTOT;
    int t = threadIdx.x;
    const float* row = qkv + (size_t)bn * 3072;
    float4 qv = *(const float4*)(row + t * 4);
    float4 kv = *(const float4*)(row + 1024 + t * 4);
    float4 vv = *(const float4*)(row + 2048 + t * 4);
    float sq = qv.x * qv.x + qv.y * qv.y + qv.z * qv.z + qv.w * qv.w;
    float sk = kv.x * kv.x + kv.y * kv.y + kv.z * kv.z + kv.w * kv.w;
    #pragma unroll
    for (int m = 1; m < 64; m <<= 1) { sq += __shfl_xor(sq, m); sk += __shfl_xor(sk, m); }
    __shared__ float redq[4], redk[4];
    int lane = t & 63, w = t >> 6;
    if (lane == 0) { redq[w] = sq; redk[w] = sk; }
    __syncthreads();
    sq = redq[0] + redq[1] + redq[2] + redq[3];
    sk = redk[0] + redk[1] + redk[2] + redk[3];
    float rsq = rsqrtf(sq * (1.f / 1024.f) + 1e-6f);
    float rsk = rsqrtf(sk * (1.f / 1024.f) + 1e-6f);
    bool is_ctx = (n < L_CTX);
    const float* qw = is_ctx ? qw_ctx : qw_in;
    const float* kw = is_ctx ? kw_ctx : kw_in;
    int col = t * 4;
    int h = col >> 6, d = col & 63;
    float c0 = cosT[n * 32 + (d >> 1)],     s0 = sinT[n * 32 + (d >> 1)];
    float c1 = cosT[n * 32 + (d >> 1) + 1], s1 = sinT[n * 32 + (d >> 1) + 1];
    size_t base = (((size_t)(b * NHEADS + h)) * NTOT + n) * HD + d;
    // Q (fold 1/sqrt(64) score scale)
    {
        float x0 = qv.x * rsq * qw[col],     x1 = qv.y * rsq * qw[col + 1];
        float x2 = qv.z * rsq * qw[col + 2], x3 = qv.w * rsq * qw[col + 3];
        float y0 = x0 * c0 - x1 * s0, y1 = x0 * s0 + x1 * c0;
        float y2 = x2 * c1 - x3 * s1, y3 = x2 * s1 + x3 * c1;
        ushort4 o; o.x = f2bf(y0 * 0.125f); o.y = f2bf(y1 * 0.125f);
        o.z = f2bf(y2 * 0.125f); o.w = f2bf(y3 * 0.125f);
        *(ushort4*)(Q + base) = o;
    }
    // K
    {
        float x0 = kv.x * rsk * kw[col],     x1 = kv.y * rsk * kw[col + 1];
        float x2 = kv.z * rsk * kw[col + 2], x3 = kv.w * rsk * kw[col + 3];
        float y0 = x0 * c0 - x1 * s0, y1 = x0 * s0 + x1 * c0;
        float y2 = x2 * c1 - x3 * s1, y3 = x2 * s1 + x3 * c1;
        ushort4 o; o.x = f2bf(y0); o.y = f2bf(y1); o.z = f2bf(y2); o.w = f2bf(y3);
        *(ushort4*)(K + base) = o;
    }
    // V transposed
    size_t vb = ((size_t)(b * NHEADS + h)) * HD;
    Vt[(vb + d + 0) * NTOT + n] = f2bf(vv.x);
    Vt[(vb + d + 1) * NTOT + n] = f2bf(vv.y);
    Vt[(vb + d + 2) * NTOT + n] = f2bf(vv.z);
    Vt[(vb + d + 3) * NTOT + n] = f2bf(vv.w);
}

// ---------------------------------------------------------------------------
// Flash attention. Grid (32 bh, 14 qtiles), 256 thr = 4 waves, 32 q-rows/wave.
// Swapped operands: S^T = mfma(K, Q) so lane owns q-row (lane&31).
// O^T = mfma(V^T, P^T). 32x32x16 bf16 MFMA throughout.
// ---------------------------------------------------------------------------
__global__ __launch_bounds__(256) void attn_kernel(
    const unsigned short* __restrict__ Q, const unsigned short* __restrict__ K,
    const unsigned short* __restrict__ Vt, const int* __restrict__ mask,
    unsigned short* __restrict__ O)
{
    int bh = blockIdx.x;
    int b = bh >> 4, h = bh & 15;
    int t = threadIdx.x, lane = t & 63, wid = t >> 6;
    int g = lane >> 5, lq = lane & 31;
    int q0 = blockIdx.y * 128 + wid * 32;
    __shared__ float mbias[L_CTX];
    if (t < L_CTX) mbias[t] = mask[b * L_CTX + t] ? 0.f : -1e30f;
    __syncthreads();
    const unsigned short* Qp = Q + (size_t)bh * NTOT * HD;
    const unsigned short* Kp = K + (size_t)bh * NTOT * HD;
    const unsigned short* Vp = Vt + (size_t)bh * HD * NTOT;

    bf16x8 qf[4];
    #pragma unroll
    for (int kk = 0; kk < 4; kk++)
        qf[kk] = *(const bf16x8*)(Qp + (size_t)(q0 + lq) * HD + kk * 16 + g * 8);

    f32x16 oacc0 = zero16(), oacc1 = zero16();
    float mrun = -1e30f, denom = 0.f;

    #pragma unroll 1
    for (int kv0 = 0; kv0 < NTOT; kv0 += 32) {
        f32x16 st = zero16();
        #pragma unroll
        for (int kk = 0; kk < 4; kk++) {
            bf16x8 kf = *(const bf16x8*)(Kp + (size_t)(kv0 + lq) * HD + kk * 16 + g * 8);
            st = __builtin_amdgcn_mfma_f32_32x32x16_bf16(kf, qf[kk], st, 0, 0, 0);
        }
        float p[16];
        float tmax = -1e30f;
        bool use_mask = (kv0 < L_CTX);
        #pragma unroll
        for (int r = 0; r < 16; r++) {
            float s = st[r];
            if (use_mask) {
                int key = kv0 + (r & 3) + 8 * (r >> 2) + 4 * g;
                s += mbias[key];
            }
            p[r] = s;
            tmax = fmaxf(tmax, s);
        }
        tmax = fmaxf(tmax, __shfl_xor(tmax, 32));
        float mnew = fmaxf(mrun, tmax);
        float corr = __expf(mrun - mnew);
        float psum = 0.f;
        #pragma unroll
        for (int r = 0; r < 16; r++) { p[r] = __expf(p[r] - mnew); psum += p[r]; }
        psum += __shfl_xor(psum, 32);
        denom = denom * corr + psum;
        mrun = mnew;
        #pragma unroll
        for (int i = 0; i < 16; i++) { oacc0[i] *= corr; oacc1[i] *= corr; }
        // pack P -> bf16 B-fragments (keys contiguous per lane-half)
        bf16x8 pf[2];
        #pragma unroll
        for (int kk = 0; kk < 2; kk++) {
            unsigned a1, b1, a2, b2;
            asm("v_cvt_pk_bf16_f32 %0, %1, %2" : "=v"(a1) : "v"(p[8 * kk + 0]), "v"(p[8 * kk + 1]));
            asm("v_cvt_pk_bf16_f32 %0, %1, %2" : "=v"(a2) : "v"(p[8 * kk + 2]), "v"(p[8 * kk + 3]));
            asm("v_cvt_pk_bf16_f32 %0, %1, %2" : "=v"(b1) : "v"(p[8 * kk + 4]), "v"(p[8 * kk + 5]));
            asm("v_cvt_pk_bf16_f32 %0, %1, %2" : "=v"(b2) : "v"(p[8 * kk + 6]), "v"(p[8 * kk + 7]));
            unsigned sa1 = __shfl_xor(a1, 32), sb1 = __shfl_xor(b1, 32);
            unsigned sa2 = __shfl_xor(a2, 32), sb2 = __shfl_xor(b2, 32);
            unsigned d0 = g ? sb1 : a1;
            unsigned d1 = g ? sb2 : a2;
            unsigned d2 = g ? b1 : sa1;
            unsigned d3 = g ? b2 : sa2;
            union { unsigned u[4]; bf16x8 v; } pu;
            pu.u[0] = d0; pu.u[1] = d1; pu.u[2] = d2; pu.u[3] = d3;
            pf[kk] = pu.v;
        }
        #pragma unroll
        for (int kk = 0; kk < 2; kk++) {
            bf16x8 v0 = *(const bf16x8*)(Vp + (size_t)(lq) * NTOT + kv0 + kk * 16 + g * 8);
            bf16x8 v1 = *(const bf16x8*)(Vp + (size_t)(32 + lq) * NTOT + kv0 + kk * 16 + g * 8);
            oacc0 = __builtin_amdgcn_mfma_f32_32x32x16_bf16(v0, pf[kk], oacc0, 0, 0, 0);
            oacc1 = __builtin_amdgcn_mfma_f32_32x32x16_bf16(v1, pf[kk], oacc1, 0, 0, 0);
        }
    }
    float inv = 1.0f / denom;
    int n = q0 + lq;
    size_t obase = ((size_t)b * NTOT + n) * DIMSZ + h * HD;
    #pragma unroll
    for (int r = 0; r < 16; r++) {
        int d = (r & 3) + 8 * (r >> 2) + 4 * g;
        O[obase + d] = f2bf(oacc0[r] * inv);
        O[obase + 32 + d] = f2bf(oacc1[r] * inv);
    }
}

// ---------------------------------------------------------------------------
extern "C" void kernel_launch(void* const* d_in, const int* in_sizes, int n_in,
                              void* d_out, int out_size, void* d_ws, size_t ws_size,
                              hipStream_t stream) {
    const float* input    = (const float*)d_in[0];
    const float* context  = (const float*)d_in[1];
    const float* cosT     = (const float*)d_in[2];
    const float* sinT     = (const float*)d_in[3];
    const float* Wqkv_in  = (const float*)d_in[4];
    const float* bqkv_in  = (const float*)d_in[5];
    const float* Wqkv_ctx = (const float*)d_in[6];
    const float* bqkv_ctx = (const float*)d_in[7];
    const float* qw_in    = (const float*)d_in[8];
    const float* kw_in    = (const float*)d_in[9];
    const float* qw_ctx   = (const float*)d_in[10];
    const float* kw_ctx   = (const float*)d_in[11];
    const float* Wo_in    = (const float*)d_in[12];
    const float* bo_in    = (const float*)d_in[13];
    const float* Wo_ctx   = (const float*)d_in[14];
    const float* bo_ctx   = (const float*)d_in[15];
    const int*   mask     = (const int*)d_in[16];

    char* ws = (char*)d_ws;
    float* qkv            = (float*)ws;                       // 44,040,192 B
    unsigned short* Qb    = (unsigned short*)(ws + 44040192); //  7,340,032 B
    unsigned short* Kb    = (unsigned short*)(ws + 51380224); //  7,340,032 B
    unsigned short* Vt    = (unsigned short*)(ws + 58720256); //  7,340,032 B
    unsigned short* Ob    = (unsigned short*)(ws + 66060288); //  7,340,032 B
    if (ws_size < 73400320) return; // loud failure instead of corruption

    float* out_in  = (float*)d_out;
    float* out_ctx = out_in + (size_t)BB * L_IN * DIMSZ;

    // QKV projections -> qkv (B, NTOT, 3072), rows [ctx(0..255); input(256..1791)]
    gemm_kernel<false><<<dim3(24, 24), 256, 0, stream>>>(
        input, Wqkv_in, bqkv_in, qkv, 3072, 1, 0, 0, 1536, 256, 256);
    gemm_kernel<false><<<dim3(4, 24), 256, 0, stream>>>(
        context, Wqkv_ctx, bqkv_ctx, qkv, 3072, 1, 0, 0, 256, 0, 1536);

    norm_rope_kernel<<<BB * NTOT, 256, 0, stream>>>(
        qkv, qw_in, kw_in, qw_ctx, kw_ctx, cosT, sinT, Qb, Kb, Vt);

    attn_kernel<<<dim3(BB * NHEADS, NTOT / 128), 256, 0, stream>>>(
        Qb, Kb, Vt, mask, Ob);

    // Output projections from O (B, NTOT, 1024) bf16
    gemm_kernel<true><<<dim3(24, 8), 256, 0, stream>>>(
        Ob, Wo_in, bo_in, out_in, 1024, 1536, 256, 256, 1, 0, 0);
    gemm_kernel<true><<<dim3(4, 8), 256, 0, stream>>>(
        Ob, Wo_ctx, bo_ctx, out_ctx, 1024, 256, 0, 1536, 1, 0, 0);
}

// Round 3
// 232.272 us; speedup vs baseline: 2.0594x; 2.0594x over previous
//
#include <hip/hip_runtime.h>
#include <stdint.h>

#define DIMSZ 1024
#define NHEADS 16
#define HD 64
#define BB 2
#define L_IN 1536
#define L_CTX 256
#define NTOT 1792   // L_CTX + L_IN
#define MROWS 3584  // BB * NTOT

typedef __attribute__((ext_vector_type(8))) short bf16x8;
typedef __attribute__((ext_vector_type(4))) float f32x4;
typedef __attribute__((ext_vector_type(16))) float f32x16;

__device__ inline unsigned short f2bf(float f) {
    union { float f; unsigned u; } v; v.f = f;
    unsigned r = v.u + 0x7fffu + ((v.u >> 16) & 1u);
    return (unsigned short)(r >> 16);
}
__device__ inline float bf2f(unsigned short u) {
    union { float f; unsigned u; } v; v.u = ((unsigned)u) << 16; return v.f;
}

__device__ inline f32x4 zero4() {
    f32x4 v;
    #pragma unroll
    for (int i = 0; i < 4; i++) v[i] = 0.f;
    return v;
}
__device__ inline f32x16 zero16() {
    f32x16 v;
    #pragma unroll
    for (int i = 0; i < 16; i++) v[i] = 0.f;
    return v;
}

// async global->LDS, 16B per lane. LDS dest must be wave-uniform base + lane*16.
#define GLL16(g, l) __builtin_amdgcn_global_load_lds( \
    (const __attribute__((address_space(1))) unsigned int*)(g), \
    (__attribute__((address_space(3))) unsigned int*)(l), 16, 0, 0)

// ---------------------------------------------------------------------------
// Pre-pass 1: convert activations fp32 -> bf16 into qkv row order.
// row r of Abuf: b = r/NTOT, ln = r%NTOT; ln<256 -> context, else input.
// ---------------------------------------------------------------------------
__global__ __launch_bounds__(256) void conv_act(
    const float* __restrict__ input, const float* __restrict__ context,
    unsigned short* __restrict__ Abuf)
{
    int idx = blockIdx.x * 256 + threadIdx.x;
    int e = idx * 4;
    int row = e >> 10, c = e & 1023;
    int b = row / NTOT, ln = row % NTOT;
    const float* src = (ln < L_CTX)
        ? context + ((size_t)b * L_CTX + ln) * 1024 + c
        : input   + ((size_t)b * L_IN + (ln - L_CTX)) * 1024 + c;
    float4 v = *(const float4*)src;
    ushort4 o; o.x = f2bf(v.x); o.y = f2bf(v.y); o.z = f2bf(v.z); o.w = f2bf(v.w);
    *(ushort4*)(Abuf + e) = o;
}

// ---------------------------------------------------------------------------
// Pre-pass 2: W (1024 x N fp32, row-major) -> Wt (N x 1024 bf16, row-major).
// 64x64 tile via LDS (pad 65 to avoid bank conflicts on column reads).
// ---------------------------------------------------------------------------
__global__ __launch_bounds__(256) void transp(
    const float* __restrict__ W, unsigned short* __restrict__ Wt, int N)
{
    __shared__ unsigned short sm[64][65];
    int k0 = blockIdx.x * 64, n0 = blockIdx.y * 64;
    int t = threadIdx.x;
    #pragma unroll
    for (int i = 0; i < 4; i++) {
        int r = (t >> 4) + i * 16, c = (t & 15) * 4;
        float4 v = *(const float4*)(W + (size_t)(k0 + r) * N + n0 + c);
        sm[r][c] = f2bf(v.x); sm[r][c + 1] = f2bf(v.y);
        sm[r][c + 2] = f2bf(v.z); sm[r][c + 3] = f2bf(v.w);
    }
    __syncthreads();
    int rn = t & 63, kc = (t >> 6) * 16;
    unsigned short* dst = Wt + (size_t)(n0 + rn) * 1024 + k0 + kc;
    #pragma unroll
    for (int q = 0; q < 4; q++) {
        ushort4 o;
        o.x = sm[kc + q * 4 + 0][rn]; o.y = sm[kc + q * 4 + 1][rn];
        o.z = sm[kc + q * 4 + 2][rn]; o.w = sm[kc + q * 4 + 3][rn];
        *(ushort4*)(dst + q * 4) = o;
    }
}

// ---------------------------------------------------------------------------
// GEMM v2: out[omap(rt,.)][n] = A[rt*128+.][k] * Wt[n][k] + bias[n]
// A: MROWSx1024 bf16 (qkv row order). Wt: NLDx1024 bf16 (per-region weight).
// 128x128 tile, BK=64, 4 waves, 16x16x32 bf16 MFMA.
// Staging: global_load_lds 16B/lane, linear LDS dest, inverse-swizzled global
// source; frag ds_read_b128 uses byte ^= (row&7)<<4 swizzle (rule 21 pair).
// Row-tile rt: b=rt/14, lrt=rt%14; lrt<2 -> ctx weights/output else in.
// ---------------------------------------------------------------------------
template<int NLD, bool OUT_BF16, bool IS_QKV>
__global__ __launch_bounds__(256, 4) void gemm2(
    const unsigned short* __restrict__ A,
    const unsigned short* __restrict__ Wt_in, const unsigned short* __restrict__ Wt_ctx,
    const float* __restrict__ bias_in, const float* __restrict__ bias_ctx,
    void* __restrict__ out_in_, void* __restrict__ out_ctx_)
{
    __shared__ __align__(16) unsigned short Asm[128 * 64];
    __shared__ __align__(16) unsigned short Bsm[128 * 64];
    const int rt = blockIdx.x, n0 = blockIdx.y * 128;
    const int b = rt / 14, lrt = rt % 14;
    const bool is_ctx = lrt < 2;
    const unsigned short* Wt = is_ctx ? Wt_ctx : Wt_in;
    const float* bias = is_ctx ? bias_ctx : bias_in;
    const int t = threadIdx.x, lane = t & 63, wid = t >> 6;
    const int wr = wid >> 1, wc = wid & 1;
    const int g4 = lane >> 4, l16 = lane & 15;

    // per-thread staging addresses: 4 chunks A + 4 chunks B, 16B each.
    // LDS byte o holds element (row=o>>7, kbyte=(o&127)^((row&7)<<4)).
    const char* asrc[4]; const char* bsrc[4];
    #pragma unroll
    for (int j = 0; j < 4; j++) {
        int o = t * 16 + j * 4096;
        int row = o >> 7;
        int cb = (o & 127) ^ ((row & 7) << 4);
        asrc[j] = (const char*)A  + ((size_t)(rt * 128 + row)) * 2048 + cb;
        bsrc[j] = (const char*)Wt + ((size_t)(n0 + row)) * 2048 + cb;
    }

    f32x4 acc[4][4];
    #pragma unroll
    for (int mi = 0; mi < 4; mi++)
        #pragma unroll
        for (int ni = 0; ni < 4; ni++) acc[mi][ni] = zero4();

    for (int ks = 0; ks < 16; ks++) {
        __syncthreads();
        #pragma unroll
        for (int j = 0; j < 4; j++) {
            int o = t * 16 + j * 4096;
            GLL16(asrc[j], (char*)Asm + o);
            GLL16(bsrc[j], (char*)Bsm + o);
            asrc[j] += 128; bsrc[j] += 128;
        }
        __syncthreads();
        #pragma unroll
        for (int kk = 0; kk < 2; kk++) {
            bf16x8 a[4], bgf[4];
            #pragma unroll
            for (int mi = 0; mi < 4; mi++) {
                int row = wr * 64 + mi * 16 + l16;
                int byte = row * 128 + ((kk * 64 + g4 * 16) ^ ((row & 7) << 4));
                a[mi] = *(const bf16x8*)((const char*)Asm + byte);
            }
            #pragma unroll
            for (int ni = 0; ni < 4; ni++) {
                int col = wc * 64 + ni * 16 + l16;
                int byte = col * 128 + ((kk * 64 + g4 * 16) ^ ((col & 7) << 4));
                bgf[ni] = *(const bf16x8*)((const char*)Bsm + byte);
            }
            #pragma unroll
            for (int mi = 0; mi < 4; mi++)
                #pragma unroll
                for (int ni = 0; ni < 4; ni++)
                    acc[mi][ni] = __builtin_amdgcn_mfma_f32_16x16x32_bf16(
                        a[mi], bgf[ni], acc[mi][ni], 0, 0, 0);
        }
    }

    // epilogue: C/D layout col=lane&15, row=(lane>>4)*4+reg
    char* optr; size_t orow0;
    if constexpr (IS_QKV) {
        optr = (char*)out_in_; orow0 = (size_t)rt * 128;
    } else {
        if (is_ctx) { optr = (char*)out_ctx_; orow0 = (size_t)b * 256 + lrt * 128; }
        else        { optr = (char*)out_in_;  orow0 = (size_t)b * 1536 + (lrt - 2) * 128; }
    }
    #pragma unroll
    for (int mi = 0; mi < 4; mi++)
        #pragma unroll
        for (int ni = 0; ni < 4; ni++) {
            int col = n0 + wc * 64 + ni * 16 + l16;
            float bv = bias[col];
            #pragma unroll
            for (int r = 0; r < 4; r++) {
                size_t row = orow0 + wr * 64 + mi * 16 + g4 * 4 + r;
                float val = acc[mi][ni][r] + bv;
                if constexpr (OUT_BF16)
                    ((unsigned short*)optr)[row * NLD + col] = f2bf(val);
                else
                    ((float*)optr)[row * NLD + col] = val;
            }
        }
}

// ---------------------------------------------------------------------------
// Fused RMSNorm + weight + RoPE + scale + layout. One block per (b,n) row.
// qkv: bf16 (B,NTOT,3072). Writes Q,K bf16 (B,H,NTOT,64), V^T bf16 (B,H,64,NTOT).
// ---------------------------------------------------------------------------
__global__ __launch_bounds__(256) void norm_rope_kernel(
    const unsigned short* __restrict__ qkv,
    const float* __restrict__ qw_in, const float* __restrict__ kw_in,
    const float* __restrict__ qw_ctx, const float* __restrict__ kw_ctx,
    const float* __restrict__ cosT, const float* __restrict__ sinT,
    unsigned short* __restrict__ Q, unsigned short* __restrict__ K,
    unsigned short* __restrict__ Vt)
{
    int bn = blockIdx.x;
    int b = bn / NTOT, n = bn % NTOT;
    int t = threadIdx.x;
    const unsigned short* row = qkv + (size_t)bn * 3072;
    ushort4 qu = *(const ushort4*)(row + t * 4);
    ushort4 ku = *(const ushort4*)(row + 1024 + t * 4);
    ushort4 vu = *(const ushort4*)(row + 2048 + t * 4);
    float q0f = bf2f(qu.x), q1f = bf2f(qu.y), q2f = bf2f(qu.z), q3f = bf2f(qu.w);
    float k0f = bf2f(ku.x), k1f = bf2f(ku.y), k2f = bf2f(ku.z), k3f = bf2f(ku.w);
    float sq = q0f * q0f + q1f * q1f + q2f * q2f + q3f * q3f;
    float sk = k0f * k0f + k1f * k1f + k2f * k2f + k3f * k3f;
    #pragma unroll
    for (int m = 1; m < 64; m <<= 1) { sq += __shfl_xor(sq, m); sk += __shfl_xor(sk, m); }
    __shared__ float redq[4], redk[4];
    int lane = t & 63, w = t >> 6;
    if (lane == 0) { redq[w] = sq; redk[w] = sk; }
    __syncthreads();
    sq = redq[0] + redq[1] + redq[2] + redq[3];
    sk = redk[0] + redk[1] + redk[2] + redk[3];
    float rsq = rsqrtf(sq * (1.f / 1024.f) + 1e-6f);
    float rsk = rsqrtf(sk * (1.f / 1024.f) + 1e-6f);
    bool is_ctx = (n < L_CTX);
    const float* qw = is_ctx ? qw_ctx : qw_in;
    const float* kw = is_ctx ? kw_ctx : kw_in;
    int col = t * 4;
    int h = col >> 6, d = col & 63;
    float c0 = cosT[n * 32 + (d >> 1)],     s0 = sinT[n * 32 + (d >> 1)];
    float c1 = cosT[n * 32 + (d >> 1) + 1], s1 = sinT[n * 32 + (d >> 1) + 1];
    size_t base = (((size_t)(b * NHEADS + h)) * NTOT + n) * HD + d;
    {
        float x0 = q0f * rsq * qw[col],     x1 = q1f * rsq * qw[col + 1];
        float x2 = q2f * rsq * qw[col + 2], x3 = q3f * rsq * qw[col + 3];
        float y0 = x0 * c0 - x1 * s0, y1 = x0 * s0 + x1 * c0;
        float y2 = x2 * c1 - x3 * s1, y3 = x2 * s1 + x3 * c1;
        ushort4 o; o.x = f2bf(y0 * 0.125f); o.y = f2bf(y1 * 0.125f);
        o.z = f2bf(y2 * 0.125f); o.w = f2bf(y3 * 0.125f);
        *(ushort4*)(Q + base) = o;
    }
    {
        float x0 = k0f * rsk * kw[col],     x1 = k1f * rsk * kw[col + 1];
        float x2 = k2f * rsk * kw[col + 2], x3 = k3f * rsk * kw[col + 3];
        float y0 = x0 * c0 - x1 * s0, y1 = x0 * s0 + x1 * c0;
        float y2 = x2 * c1 - x3 * s1, y3 = x2 * s1 + x3 * c1;
        ushort4 o; o.x = f2bf(y0); o.y = f2bf(y1); o.z = f2bf(y2); o.w = f2bf(y3);
        *(ushort4*)(K + base) = o;
    }
    size_t vb = ((size_t)(b * NHEADS + h)) * HD;
    Vt[(vb + d + 0) * NTOT + n] = vu.x;
    Vt[(vb + d + 1) * NTOT + n] = vu.y;
    Vt[(vb + d + 2) * NTOT + n] = vu.z;
    Vt[(vb + d + 3) * NTOT + n] = vu.w;
}

// ---------------------------------------------------------------------------
// Flash attention. Grid (32 bh, 14 qtiles), 256 thr = 4 waves, 32 q-rows/wave.
// Swapped operands: S^T = mfma(K, Q) so lane owns q-row (lane&31).
// O^T = mfma(V^T, P^T). 32x32x16 bf16 MFMA throughout.
// ---------------------------------------------------------------------------
__global__ __launch_bounds__(256) void attn_kernel(
    const unsigned short* __restrict__ Q, const unsigned short* __restrict__ K,
    const unsigned short* __restrict__ Vt, const int* __restrict__ mask,
    unsigned short* __restrict__ O)
{
    int bh = blockIdx.x;
    int b = bh >> 4, h = bh & 15;
    int t = threadIdx.x, lane = t & 63, wid = t >> 6;
    int g = lane >> 5, lq = lane & 31;
    int q0 = blockIdx.y * 128 + wid * 32;
    __shared__ float mbias[L_CTX];
    if (t < L_CTX) mbias[t] = mask[b * L_CTX + t] ? 0.f : -1e30f;
    __syncthreads();
    const unsigned short* Qp = Q + (size_t)bh * NTOT * HD;
    const unsigned short* Kp = K + (size_t)bh * NTOT * HD;
    const unsigned short* Vp = Vt + (size_t)bh * HD * NTOT;

    bf16x8 qf[4];
    #pragma unroll
    for (int kk = 0; kk < 4; kk++)
        qf[kk] = *(const bf16x8*)(Qp + (size_t)(q0 + lq) * HD + kk * 16 + g * 8);

    f32x16 oacc0 = zero16(), oacc1 = zero16();
    float mrun = -1e30f, denom = 0.f;

    #pragma unroll 1
    for (int kv0 = 0; kv0 < NTOT; kv0 += 32) {
        f32x16 st = zero16();
        #pragma unroll
        for (int kk = 0; kk < 4; kk++) {
            bf16x8 kf = *(const bf16x8*)(Kp + (size_t)(kv0 + lq) * HD + kk * 16 + g * 8);
            st = __builtin_amdgcn_mfma_f32_32x32x16_bf16(kf, qf[kk], st, 0, 0, 0);
        }
        float p[16];
        float tmax = -1e30f;
        bool use_mask = (kv0 < L_CTX);
        #pragma unroll
        for (int r = 0; r < 16; r++) {
            float s = st[r];
            if (use_mask) {
                int key = kv0 + (r & 3) + 8 * (r >> 2) + 4 * g;
                s += mbias[key];
            }
            p[r] = s;
            tmax = fmaxf(tmax, s);
        }
        tmax = fmaxf(tmax, __shfl_xor(tmax, 32));
        float mnew = fmaxf(mrun, tmax);
        float corr = __expf(mrun - mnew);
        float psum = 0.f;
        #pragma unroll
        for (int r = 0; r < 16; r++) { p[r] = __expf(p[r] - mnew); psum += p[r]; }
        psum += __shfl_xor(psum, 32);
        denom = denom * corr + psum;
        mrun = mnew;
        #pragma unroll
        for (int i = 0; i < 16; i++) { oacc0[i] *= corr; oacc1[i] *= corr; }
        bf16x8 pf[2];
        #pragma unroll
        for (int kk = 0; kk < 2; kk++) {
            unsigned a1, b1, a2, b2;
            asm("v_cvt_pk_bf16_f32 %0, %1, %2" : "=v"(a1) : "v"(p[8 * kk + 0]), "v"(p[8 * kk + 1]));
            asm("v_cvt_pk_bf16_f32 %0, %1, %2" : "=v"(a2) : "v"(p[8 * kk + 2]), "v"(p[8 * kk + 3]));
            asm("v_cvt_pk_bf16_f32 %0, %1, %2" : "=v"(b1) : "v"(p[8 * kk + 4]), "v"(p[8 * kk + 5]));
            asm("v_cvt_pk_bf16_f32 %0, %1, %2" : "=v"(b2) : "v"(p[8 * kk + 6]), "v"(p[8 * kk + 7]));
            unsigned sa1 = __shfl_xor(a1, 32), sb1 = __shfl_xor(b1, 32);
            unsigned sa2 = __shfl_xor(a2, 32), sb2 = __shfl_xor(b2, 32);
            unsigned d0 = g ? sb1 : a1;
            unsigned d1 = g ? sb2 : a2;
            unsigned d2 = g ? b1 : sa1;
            unsigned d3 = g ? b2 : sa2;
            union { unsigned u[4]; bf16x8 v; } pu;
            pu.u[0] = d0; pu.u[1] = d1; pu.u[2] = d2; pu.u[3] = d3;
            pf[kk] = pu.v;
        }
        #pragma unroll
        for (int kk = 0; kk < 2; kk++) {
            bf16x8 v0 = *(const bf16x8*)(Vp + (size_t)(lq) * NTOT + kv0 + kk * 16 + g * 8);
            bf16x8 v1 = *(const bf16x8*)(Vp + (size_t)(32 + lq) * NTOT + kv0 + kk * 16 + g * 8);
            oacc0 = __builtin_amdgcn_mfma_f32_32x32x16_bf16(v0, pf[kk], oacc0, 0, 0, 0);
            oacc1 = __builtin_amdgcn_mfma_f32_32x32x16_bf16(v1, pf[kk], oacc1, 0, 0, 0);
        }
    }
    float inv = 1.0f / denom;
    int n = q0 + lq;
    size_t obase = ((size_t)b * NTOT + n) * DIMSZ + h * HD;
    #pragma unroll
    for (int r = 0; r < 16; r++) {
        int d = (r & 3) + 8 * (r >> 2) + 4 * g;
        O[obase + d] = f2bf(oacc0[r] * inv);
        O[obase + 32 + d] = f2bf(oacc1[r] * inv);
    }
}

// ---------------------------------------------------------------------------
extern "C" void kernel_launch(void* const* d_in, const int* in_sizes, int n_in,
                              void* d_out, int out_size, void* d_ws, size_t ws_size,
                              hipStream_t stream) {
    const float* input    = (const float*)d_in[0];
    const float* context  = (const float*)d_in[1];
    const float* cosT     = (const float*)d_in[2];
    const float* sinT     = (const float*)d_in[3];
    const float* Wqkv_in  = (const float*)d_in[4];
    const float* bqkv_in  = (const float*)d_in[5];
    const float* Wqkv_ctx = (const float*)d_in[6];
    const float* bqkv_ctx = (const float*)d_in[7];
    const float* qw_in    = (const float*)d_in[8];
    const float* kw_in    = (const float*)d_in[9];
    const float* qw_ctx   = (const float*)d_in[10];
    const float* kw_ctx   = (const float*)d_in[11];
    const float* Wo_in    = (const float*)d_in[12];
    const float* bo_in    = (const float*)d_in[13];
    const float* Wo_ctx   = (const float*)d_in[14];
    const float* bo_ctx   = (const float*)d_in[15];
    const int*   mask     = (const int*)d_in[16];

    // Workspace layout (aliased regions; all bf16 except noted):
    //  [0)            WoT_in   1024x1024          2,097,152
    //  [2,097,152)    WoT_ctx  1024x1024          2,097,152
    //  [4,194,304)    qkvb     3584x3072         22,020,096
    //  [26,214,400)   U-region (two lifetimes):
    //    phase1: Abuf 3584x1024 (7,340,032) | WqT_in (6,291,456) | WqT_ctx (6,291,456)
    //    phase2: Qb (7,340,032) | Kb (7,340,032) | Vt (7,340,032) | Ob (7,340,032)
    char* ws = (char*)d_ws;
    unsigned short* WoT_in  = (unsigned short*)(ws);
    unsigned short* WoT_ctx = (unsigned short*)(ws + 2097152);
    unsigned short* qkvb    = (unsigned short*)(ws + 4194304);
    char* U = ws + 26214400;
    unsigned short* Abuf    = (unsigned short*)(U);
    unsigned short* WqT_in  = (unsigned short*)(U + 7340032);
    unsigned short* WqT_ctx = (unsigned short*)(U + 13631488);
    unsigned short* Qb      = (unsigned short*)(U);
    unsigned short* Kb      = (unsigned short*)(U + 7340032);
    unsigned short* Vt      = (unsigned short*)(U + 14680064);
    unsigned short* Ob      = (unsigned short*)(U + 22020096);
    if (ws_size < 55574528) return; // loud failure instead of corruption

    float* out_in  = (float*)d_out;
    float* out_ctx = out_in + (size_t)BB * L_IN * DIMSZ;

    conv_act<<<MROWS, 256, 0, stream>>>(input, context, Abuf);
    transp<<<dim3(16, 48), 256, 0, stream>>>(Wqkv_in,  WqT_in,  3072);
    transp<<<dim3(16, 48), 256, 0, stream>>>(Wqkv_ctx, WqT_ctx, 3072);
    transp<<<dim3(16, 16), 256, 0, stream>>>(Wo_in,  WoT_in,  1024);
    transp<<<dim3(16, 16), 256, 0, stream>>>(Wo_ctx, WoT_ctx, 1024);

    gemm2<3072, true, true><<<dim3(28, 24), 256, 0, stream>>>(
        Abuf, WqT_in, WqT_ctx, bqkv_in, bqkv_ctx, qkvb, qkvb);

    norm_rope_kernel<<<MROWS, 256, 0, stream>>>(
        qkvb, qw_in, kw_in, qw_ctx, kw_ctx, cosT, sinT, Qb, Kb, Vt);

    attn_kernel<<<dim3(BB * NHEADS, NTOT / 128), 256, 0, stream>>>(
        Qb, Kb, Vt, mask, Ob);

    gemm2<1024, false, false><<<dim3(28, 8), 256, 0, stream>>>(
        Ob, WoT_in, WoT_ctx, bo_in, bo_ctx, out_in, out_ctx);
}